// Round 3
// baseline (315.520 us; speedup 1.0000x reference)
//
#include <hip/hip_runtime.h>
#include <hip/hip_fp16.h>

#define D_STATE 64
#define L_SEQ   4096
#define D_MODEL 512
#define BATCH   4

typedef _Float16 half8 __attribute__((ext_vector_type(8)));
typedef float f32x4 __attribute__((ext_vector_type(4)));

// Kr tables: Kr[i] = K[4095-i] for i<=4095, 0 for 4096..4351 (guard).
#define KR_LEN 4352
#define KR_BYTES (KR_LEN * 2)
#define UPK_BYTES ((size_t)64 * 2048 * 64 * 2)  // 16 MiB per table

typedef const __attribute__((address_space(1))) void* gas_ptr;
typedef __attribute__((address_space(3))) void* las_ptr;

// ===========================================================================
// Kernel 1: compute K[m] = c^T A^m b, emit reversed split f16 hi/lo tables.
// ===========================================================================
__global__ __launch_bounds__(256) void k_prep_f16(
    const float* __restrict__ A, const float* __restrict__ B,
    const float* __restrict__ C, __half* __restrict__ Kr_hi,
    __half* __restrict__ Kr_lo) {
  __shared__ float Ma[64][68];
  __shared__ float Mb[64][68];
  __shared__ float As[64][68];
  __shared__ float vrT[64][68];
  __shared__ float cqT[64][68];

  const int tid = threadIdx.x;
  Kr_hi[4096 + tid] = (__half)0.0f;
  Kr_lo[4096 + tid] = (__half)0.0f;

  for (int e = tid; e < 4096; e += 256) {
    const int i = e >> 6, j = e & 63;
    const float a = A[e];
    Ma[i][j] = a;
    As[i][j] = a;
  }
  __syncthreads();

  const int iy = tid >> 4, jx = tid & 15;
  const int iy4 = iy * 4, jx4 = jx * 4;
  for (int it = 0; it < 6; ++it) {
    float (*src)[68] = (it & 1) ? Mb : Ma;
    float (*dst)[68] = (it & 1) ? Ma : Mb;
    float acc[4][4] = {{0.f}};
#pragma unroll 8
    for (int k = 0; k < 64; ++k) {
      const float a0 = src[iy4 + 0][k];
      const float a1 = src[iy4 + 1][k];
      const float a2 = src[iy4 + 2][k];
      const float a3 = src[iy4 + 3][k];
      const float4 b4 = *(const float4*)&src[k][jx4];
      acc[0][0] += a0 * b4.x; acc[0][1] += a0 * b4.y; acc[0][2] += a0 * b4.z; acc[0][3] += a0 * b4.w;
      acc[1][0] += a1 * b4.x; acc[1][1] += a1 * b4.y; acc[1][2] += a1 * b4.z; acc[1][3] += a1 * b4.w;
      acc[2][0] += a2 * b4.x; acc[2][1] += a2 * b4.y; acc[2][2] += a2 * b4.z; acc[2][3] += a2 * b4.w;
      acc[3][0] += a3 * b4.x; acc[3][1] += a3 * b4.y; acc[3][2] += a3 * b4.z; acc[3][3] += a3 * b4.w;
    }
#pragma unroll
    for (int r = 0; r < 4; ++r)
#pragma unroll
      for (int c = 0; c < 4; ++c) dst[iy4 + r][jx4 + c] = acc[r][c];
    __syncthreads();
  }

  const int lane = tid & 63;
  const int wave = tid >> 6;
  if (wave < 2) {
    float reg[64];
    float cur;
    if (wave == 0) {
#pragma unroll
      for (int j = 0; j < 64; ++j) reg[j] = As[lane][j];
      cur = B[lane];
      vrT[lane][0] = cur;
    } else {
#pragma unroll
      for (int j = 0; j < 64; ++j) reg[j] = Ma[j][lane];
      cur = C[lane];
      cqT[lane][0] = cur;
    }
    for (int stp = 1; stp < 64; ++stp) {
      float nv = 0.f;
#pragma unroll
      for (int j = 0; j < 64; ++j) {
        const float bj =
            __int_as_float(__builtin_amdgcn_readlane(__float_as_int(cur), j));
        nv += reg[j] * bj;
      }
      cur = nv;
      if (wave == 0) vrT[lane][stp] = cur;
      else           cqT[lane][stp] = cur;
    }
  }
  __syncthreads();

  {
    float acc[4][4] = {{0.f}};
#pragma unroll 8
    for (int i = 0; i < 64; ++i) {
      const float4 a4 = *(const float4*)&cqT[i][iy4];
      const float4 b4 = *(const float4*)&vrT[i][jx4];
      acc[0][0] += a4.x * b4.x; acc[0][1] += a4.x * b4.y; acc[0][2] += a4.x * b4.z; acc[0][3] += a4.x * b4.w;
      acc[1][0] += a4.y * b4.x; acc[1][1] += a4.y * b4.y; acc[1][2] += a4.y * b4.z; acc[1][3] += a4.y * b4.w;
      acc[2][0] += a4.z * b4.x; acc[2][1] += a4.z * b4.y; acc[2][2] += a4.z * b4.z; acc[2][3] += a4.z * b4.w;
      acc[3][0] += a4.w * b4.x; acc[3][1] += a4.w * b4.y; acc[3][2] += a4.w * b4.z; acc[3][3] += a4.w * b4.w;
    }
#pragma unroll
    for (int r = 0; r < 4; ++r)
#pragma unroll
      for (int c = 0; c < 4; ++c) {
        const int m = (iy4 + r) * 64 + jx4 + c;
        const float v = acc[r][c];
        const _Float16 hh = (_Float16)v;
        const _Float16 ll = (_Float16)(v - (float)hh);
        Kr_hi[4095 - m] = *(const __half*)&hh;
        Kr_lo[4095 - m] = *(const __half*)&ll;
      }
  }
}

// ===========================================================================
// Kernel 2: split u into f16 hi/lo, transpose to Upk[kt][s][kk].
// LDS transpose with odd stride (conflict-free), FULLY COALESCED stores:
// consecutive lanes write consecutive 16B chunks (1 KB/instr contiguous).
// ===========================================================================
__global__ __launch_bounds__(256) void k_usplit(
    const float* __restrict__ u, __half* __restrict__ Upk_hi,
    __half* __restrict__ Upk_lo) {
  __shared__ float Uts[64][65];  // Uts[s][k] = u[t0+k][d0+s]; stride 65 (odd)
  const int tt = blockIdx.x;     // t-tile 0..63
  const int sb = blockIdx.y;     // s-tile 0..31
  const int tid = threadIdx.x;
  const int s0g = sb * 64;
  const int b = s0g >> 9, d0 = s0g & 511;
  const float* ub = u + ((size_t)b * L_SEQ + tt * 64) * D_MODEL + d0;

#pragma unroll
  for (int i = 0; i < 4; ++i) {
    const int c = tid + 256 * i;  // 1024 float4 chunks (64 t-rows x 16)
    const int k = c >> 4, s4 = (c & 15) * 4;
    const float4 v = *(const float4*)(ub + (size_t)k * D_MODEL + s4);
    Uts[s4 + 0][k] = v.x;
    Uts[s4 + 1][k] = v.y;
    Uts[s4 + 2][k] = v.z;
    Uts[s4 + 3][k] = v.w;
  }
  __syncthreads();

#pragma unroll
  for (int it = 0; it < 2; ++it) {
    const int c = tid + 256 * it;  // 512 output chunks (64 s x 8 kc)
    const int sl = c >> 3, kc = c & 7;
    half8 h, l;
#pragma unroll
    for (int j = 0; j < 8; ++j) {
      const float x = Uts[sl][kc * 8 + j];
      const _Float16 hh = (_Float16)x;
      h[j] = hh;
      l[j] = (_Float16)(x - (float)hh);
    }
    const size_t off = ((size_t)tt * 2048 + s0g + sl) * 64 + kc * 8;
    *(half8*)(Upk_hi + off) = h;   // lanes -> consecutive 16B: coalesced
    *(half8*)(Upk_lo + off) = l;
  }
}

// ===========================================================================
// Kernel 3: y = T * U via split-f16 MFMA.
// 128x128 tile; 4 waves, each 128 rows x 32 cols (col-exclusive -> LDS reads
// halved). Balanced grid: block = (pair, sg) handles row-tiles pair and
// 31-pair sequentially -> 66 k-tiles for every block. Double-buffered LDS
// staged with global_load_lds (16B), XOR-swizzled stride-64 layout.
// A-fragments direct from L1-resident reversed Kr tables.
// ===========================================================================
__global__ __launch_bounds__(256) void k_conv_f16(
    const __half* __restrict__ Upk_hi, const __half* __restrict__ Upk_lo,
    const __half* __restrict__ Kr_hi, const __half* __restrict__ Kr_lo,
    float* __restrict__ out) {
  // [buf(2)][table(2)][s(128)][chunk(8)x16B] = 64 KB
  __shared__ __align__(16) char Bs[65536];

  // XCD swizzle: XCD x (= blockIdx%8) hosts sg {2x, 2x+1} -> its 4 MB
  // column stripe of Upk stays L2-local.
  const int Bx = blockIdx.x;
  const int xcd = Bx & 7;
  const int slot = Bx >> 3;           // 0..31
  const int sg = xcd * 2 + (slot >> 4);
  const int pair = slot & 15;
  const int s0 = sg * 128;

  const int tid = threadIdx.x;
  const int lane = tid & 63;
  const int wave = tid >> 6;
  const int lid = lane & 15;
  const int quad = lane >> 4;
  const int wc = wave * 32;

  // --- staging address precompute: 8 global_load_lds per wave per kt ---
  int goffs[8];  // byte offsets within one (kt, table) slab (incl. s0)
#pragma unroll
  for (int i = 0; i < 8; ++i) {
    const int ct = (wave & 1) * 512 + i * 64 + lane;  // chunk within table
    const int s = ct >> 3, cl = ct & 7;
    const int cg = cl ^ (s & 7);                      // XOR swizzle
    goffs[i] = (s * 64 + cg * 8) * 2;
  }
  const __half* gtab = (wave >> 1) ? Upk_lo : Upk_hi;
  const char* gslab0 = (const char*)gtab + (size_t)s0 * 128;
  const int lwb = wave * 8192;  // lds byte base for this wave's instrs

  // --- reader LDS byte offsets (buf added at use) ---
  int boffH[2][2], boffL[2][2];
#pragma unroll
  for (int in = 0; in < 2; ++in)
#pragma unroll
    for (int step = 0; step < 2; ++step) {
      const int s = wc + in * 16 + lid;
      const int cl = (step * 4 + quad) ^ (s & 7);
      boffH[in][step] = s * 128 + cl * 16;
      boffL[in][step] = 16384 + s * 128 + cl * 16;
    }

#define STAGE(kt_, buf_)                                                     \
  {                                                                          \
    const char* gs_ = gslab0 + (size_t)(kt_)*262144;                         \
    const int lb_ = (buf_)*32768 + lwb;                                      \
    _Pragma("unroll") for (int i_ = 0; i_ < 8; ++i_) {                       \
      __builtin_amdgcn_global_load_lds((gas_ptr)(gs_ + goffs[i_]),           \
                                       (las_ptr)(&Bs[lb_ + i_ * 1024]), 16,  \
                                       0, 0);                                \
    }                                                                        \
  }

  for (int ph = 0; ph < 2; ++ph) {
    const int tr = ph ? (31 - pair) : pair;
    const int nk = 2 * (tr + 1);
    const int t0 = tr * 128;

    f32x4 acc[8][2];
#pragma unroll
    for (int im = 0; im < 8; ++im)
#pragma unroll
      for (int in = 0; in < 2; ++in) acc[im][in] = (f32x4)(0.f);

    STAGE(0, 0);
    __syncthreads();

    for (int kt = 0; kt < nk; ++kt) {
      const int buf = kt & 1;
      if (kt + 1 < nk) STAGE(kt + 1, buf ^ 1);  // async prefetch next tile

      const int g0 = 4095 - t0 + kt * 64;
#pragma unroll
      for (int step = 0; step < 2; ++step) {
        const int kq = step * 32 + quad * 8;
        half8 ah[8], al[8], bh[2], bl[2];
#pragma unroll
        for (int f = 0; f < 8; ++f) {
          const int idx = g0 - (f * 16 + lid) + kq;  // in [0, 4344]
          __builtin_memcpy(&ah[f], Kr_hi + idx, 16);
          __builtin_memcpy(&al[f], Kr_lo + idx, 16);
        }
#pragma unroll
        for (int in = 0; in < 2; ++in) {
          bh[in] = *(const half8*)&Bs[buf * 32768 + boffH[in][step]];
          bl[in] = *(const half8*)&Bs[buf * 32768 + boffL[in][step]];
        }
#pragma unroll
        for (int im = 0; im < 8; ++im)
#pragma unroll
          for (int in = 0; in < 2; ++in) {
            acc[im][in] = __builtin_amdgcn_mfma_f32_16x16x32_f16(
                ah[im], bh[in], acc[im][in], 0, 0, 0);
            acc[im][in] = __builtin_amdgcn_mfma_f32_16x16x32_f16(
                ah[im], bl[in], acc[im][in], 0, 0, 0);
            acc[im][in] = __builtin_amdgcn_mfma_f32_16x16x32_f16(
                al[im], bh[in], acc[im][in], 0, 0, 0);
          }
      }
      __syncthreads();  // drains next-tile loads (issued ~500 cyc ago)
    }

    // epilogue (LDS untouched; next phase's STAGE(0,0) is safe after the
    // last barrier above)
#pragma unroll
    for (int in = 0; in < 2; ++in) {
      const int s = s0 + wc + in * 16 + lid;
      const int bi = s >> 9, d = s & 511;
      float* op = out + (size_t)bi * L_SEQ * D_MODEL + d;
#pragma unroll
      for (int im = 0; im < 8; ++im)
#pragma unroll
        for (int r = 0; r < 4; ++r)
          op[(size_t)(t0 + im * 16 + quad * 4 + r) * D_MODEL] = acc[im][in][r];
    }
  }
#undef STAGE
}

// ===========================================================================
// Fallback fp32 path (round-1 kernels, used only if ws is too small)
// ===========================================================================
__global__ __launch_bounds__(256) void k_precompute_f32(
    const float* __restrict__ A, const float* __restrict__ B,
    const float* __restrict__ C, float* __restrict__ Kker) {
  __shared__ float Ma[64][68];
  __shared__ float Mb[64][68];
  __shared__ float As[64][68];
  __shared__ float vrT[64][68];
  __shared__ float cqT[64][68];
  __shared__ __align__(16) float vcur[64];
  __shared__ __align__(16) float ccur[64];

  const int tid = threadIdx.x;
  for (int e = tid; e < 4096; e += 256) {
    const int i = e >> 6, j = e & 63;
    const float a = A[e];
    Ma[i][j] = a;
    As[i][j] = a;
  }
  __syncthreads();
  const int iy = tid >> 4, jx = tid & 15;
  const int iy4 = iy * 4, jx4 = jx * 4;
  for (int it = 0; it < 6; ++it) {
    float (*src)[68] = (it & 1) ? Mb : Ma;
    float (*dst)[68] = (it & 1) ? Ma : Mb;
    float acc[4][4] = {{0.f}};
#pragma unroll 8
    for (int k = 0; k < 64; ++k) {
      const float a0 = src[iy4 + 0][k];
      const float a1 = src[iy4 + 1][k];
      const float a2 = src[iy4 + 2][k];
      const float a3 = src[iy4 + 3][k];
      const float4 b4 = *(const float4*)&src[k][jx4];
      acc[0][0] += a0 * b4.x; acc[0][1] += a0 * b4.y; acc[0][2] += a0 * b4.z; acc[0][3] += a0 * b4.w;
      acc[1][0] += a1 * b4.x; acc[1][1] += a1 * b4.y; acc[1][2] += a1 * b4.z; acc[1][3] += a1 * b4.w;
      acc[2][0] += a2 * b4.x; acc[2][1] += a2 * b4.y; acc[2][2] += a2 * b4.z; acc[2][3] += a2 * b4.w;
      acc[3][0] += a3 * b4.x; acc[3][1] += a3 * b4.y; acc[3][2] += a3 * b4.z; acc[3][3] += a3 * b4.w;
    }
#pragma unroll
    for (int r = 0; r < 4; ++r)
#pragma unroll
      for (int c = 0; c < 4; ++c) dst[iy4 + r][jx4 + c] = acc[r][c];
    __syncthreads();
  }
  float row[64];
  if (tid < 64) {
#pragma unroll
    for (int j = 0; j < 64; ++j) row[j] = As[tid][j];
    vcur[tid] = B[tid];
    vrT[tid][0] = B[tid];
  } else if (tid < 128) {
    const int i = tid - 64;
#pragma unroll
    for (int j = 0; j < 64; ++j) row[j] = Ma[j][i];
    ccur[i] = C[i];
    cqT[i][0] = C[i];
  }
  __syncthreads();
  for (int stp = 1; stp < 64; ++stp) {
    float nv = 0.f;
    if (tid < 128) {
      const float* sv = (tid < 64) ? vcur : ccur;
      float a0 = 0.f, a1 = 0.f, a2 = 0.f, a3 = 0.f;
#pragma unroll
      for (int j = 0; j < 64; j += 4) {
        const float4 x = *(const float4*)&sv[j];
        a0 += row[j + 0] * x.x;
        a1 += row[j + 1] * x.y;
        a2 += row[j + 2] * x.z;
        a3 += row[j + 3] * x.w;
      }
      nv = (a0 + a1) + (a2 + a3);
    }
    __syncthreads();
    if (tid < 64) {
      vcur[tid] = nv;
      vrT[tid][stp] = nv;
    } else if (tid < 128) {
      const int i = tid - 64;
      ccur[i] = nv;
      cqT[i][stp] = nv;
    }
    __syncthreads();
  }
  {
    float acc[4][4] = {{0.f}};
#pragma unroll 8
    for (int i = 0; i < 64; ++i) {
      const float4 a4 = *(const float4*)&cqT[i][iy4];
      const float4 b4 = *(const float4*)&vrT[i][jx4];
      acc[0][0] += a4.x * b4.x; acc[0][1] += a4.x * b4.y; acc[0][2] += a4.x * b4.z; acc[0][3] += a4.x * b4.w;
      acc[1][0] += a4.y * b4.x; acc[1][1] += a4.y * b4.y; acc[1][2] += a4.y * b4.z; acc[1][3] += a4.y * b4.w;
      acc[2][0] += a4.z * b4.x; acc[2][1] += a4.z * b4.y; acc[2][2] += a4.z * b4.z; acc[2][3] += a4.z * b4.w;
      acc[3][0] += a4.w * b4.x; acc[3][1] += a4.w * b4.y; acc[3][2] += a4.w * b4.z; acc[3][3] += a4.w * b4.w;
    }
#pragma unroll
    for (int r = 0; r < 4; ++r) {
      float4 v;
      v.x = acc[r][0]; v.y = acc[r][1]; v.z = acc[r][2]; v.w = acc[r][3];
      *(float4*)&Kker[(iy4 + r) * 64 + jx4] = v;
    }
  }
}

__global__ __launch_bounds__(256) void k_conv_f32(
    const float* __restrict__ u, const float* __restrict__ Kker,
    float* __restrict__ out) {
  __shared__ float As2[64][68];
  __shared__ float Us[64][68];
  const int sg = blockIdx.x;
  const int tr = (int)(gridDim.y - 1) - (int)blockIdx.y;
  const int t0 = tr * 64;
  const int s0 = sg * 64;
  const int b = s0 >> 9;
  const int d0 = s0 & 511;
  const float* __restrict__ ub = u + (size_t)b * L_SEQ * D_MODEL + d0;
  float* __restrict__ ob = out + (size_t)b * L_SEQ * D_MODEL + d0;
  const int tid = threadIdx.x;
  const int ty = tid >> 4, tx = tid & 15;
  const int ty4 = ty * 4, tx4 = tx * 4;
  float acc[4][4] = {{0.f}};
  const int nk = tr + 1;
  for (int kt = 0; kt < nk; ++kt) {
    const int k0 = kt * 64;
    const int diff0 = t0 - k0;
    for (int e = tid; e < 64 * 16; e += 256) {
      const int kk = e >> 4, j4 = (e & 15) * 4;
      *(float4*)&Us[kk][j4] =
          *(const float4*)&ub[(size_t)(k0 + kk) * D_MODEL + j4];
    }
    for (int e = tid; e < 64 * 64; e += 256) {
      const int kk = e >> 6, i = e & 63;
      const int idx = diff0 + i - kk;
      As2[kk][i] = (idx >= 0) ? Kker[idx] : 0.f;
    }
    __syncthreads();
#pragma unroll 8
    for (int kk = 0; kk < 64; ++kk) {
      const float4 a4 = *(const float4*)&As2[kk][ty4];
      const float4 b4 = *(const float4*)&Us[kk][tx4];
      acc[0][0] += a4.x * b4.x; acc[0][1] += a4.x * b4.y; acc[0][2] += a4.x * b4.z; acc[0][3] += a4.x * b4.w;
      acc[1][0] += a4.y * b4.x; acc[1][1] += a4.y * b4.y; acc[1][2] += a4.y * b4.z; acc[1][3] += a4.y * b4.w;
      acc[2][0] += a4.z * b4.x; acc[2][1] += a4.z * b4.y; acc[2][2] += a4.z * b4.z; acc[2][3] += a4.z * b4.w;
      acc[3][0] += a4.w * b4.x; acc[3][1] += a4.w * b4.y; acc[3][2] += a4.w * b4.z; acc[3][3] += a4.w * b4.w;
    }
    __syncthreads();
  }
#pragma unroll
  for (int r = 0; r < 4; ++r) {
    float4 v;
    v.x = acc[r][0]; v.y = acc[r][1]; v.z = acc[r][2]; v.w = acc[r][3];
    *(float4*)&ob[(size_t)(t0 + ty4 + r) * D_MODEL + tx4] = v;
  }
}

extern "C" void kernel_launch(void* const* d_in, const int* in_sizes, int n_in,
                              void* d_out, int out_size, void* d_ws,
                              size_t ws_size, hipStream_t stream) {
  const float* u = (const float*)d_in[0];
  const float* A = (const float*)d_in[1];
  const float* B = (const float*)d_in[2];
  const float* C = (const float*)d_in[3];
  float* out = (float*)d_out;

  const size_t need = 2 * KR_BYTES + 2 * UPK_BYTES;  // ~33.6 MB
  if (ws_size >= need) {
    __half* Kr_hi = (__half*)d_ws;
    __half* Kr_lo = (__half*)((char*)d_ws + KR_BYTES);
    __half* Upk_hi = (__half*)((char*)d_ws + 2 * KR_BYTES);
    __half* Upk_lo = (__half*)((char*)d_ws + 2 * KR_BYTES + UPK_BYTES);
    k_prep_f16<<<1, 256, 0, stream>>>(A, B, C, Kr_hi, Kr_lo);
    k_usplit<<<dim3(64, 32), 256, 0, stream>>>(u, Upk_hi, Upk_lo);
    k_conv_f16<<<256, 256, 0, stream>>>(Upk_hi, Upk_lo, Kr_hi, Kr_lo, out);
  } else {
    float* Kker = (float*)d_ws;
    k_precompute_f32<<<1, 256, 0, stream>>>(A, B, C, Kker);
    k_conv_f32<<<dim3(32, 64), 256, 0, stream>>>(u, Kker, out);
  }
}

// Round 4
// 246.632 us; speedup vs baseline: 1.2793x; 1.2793x over previous
//
#include <hip/hip_runtime.h>

#define L_SEQ   4096
#define D_MODEL 512
#define NSEQ    2048   // BATCH * D_MODEL
#define CH      128    // chunk length
#define NC      32     // chunks

// workspace float offsets
#define OFF_P    0        // P = A^128, [i][j] row-major, 4096
#define OFF_W1   4096     // W1[i][r] = (A^{127-r} b)[i], 64x128
#define OFF_WOUT 12288    // Wout[i][r] = (c^T A^{r+1})[i], 64x128
#define OFF_KLOC 20480    // KlocZ[0..127]=0, KlocZ[128+m]=c^T A^m b, 256
#define OFF_XS   20736    // xs[c][i][s], 32*64*2048

#define BC(v, j) __int_as_float(__builtin_amdgcn_readlane(__float_as_int(v), (j)))

// ===========================================================================
// k_prep (1 block): P=A^128 via 7 LDS squarings; four 64-step chains in 4
// parallel waves (halves split via A^64): W1, Wout, Kloc tables.
// ===========================================================================
__global__ __launch_bounds__(256) void k_prep(
    const float* __restrict__ A, const float* __restrict__ B,
    const float* __restrict__ C, float* __restrict__ ws) {
  __shared__ float M0[64][68];
  __shared__ float M1[64][68];
  __shared__ float Asv[64][68];
  __shared__ float vrT[128][65];  // vrT[m][i] = (A^m b)[i]
  __shared__ float Cs[64], Bsh[64];

  const int tid = threadIdx.x;
  if (tid < 64) { Cs[tid] = C[tid]; Bsh[tid] = B[tid]; }
  for (int e = tid; e < 4096; e += 256) {
    const float a = A[e];
    M0[e >> 6][e & 63] = a;
    Asv[e >> 6][e & 63] = a;
  }
  __syncthreads();

  // 7 squarings: after it=5 M0=A^64, after it=6 M1=A^128
  const int iy4 = (tid >> 4) * 4, jx4 = (tid & 15) * 4;
  for (int it = 0; it < 7; ++it) {
    float (*src)[68] = (it & 1) ? M1 : M0;
    float (*dst)[68] = (it & 1) ? M0 : M1;
    float acc[4][4] = {{0.f}};
#pragma unroll 8
    for (int k = 0; k < 64; ++k) {
      const float a0 = src[iy4 + 0][k];
      const float a1 = src[iy4 + 1][k];
      const float a2 = src[iy4 + 2][k];
      const float a3 = src[iy4 + 3][k];
      const float4 b4 = *(const float4*)&src[k][jx4];
      acc[0][0] += a0 * b4.x; acc[0][1] += a0 * b4.y; acc[0][2] += a0 * b4.z; acc[0][3] += a0 * b4.w;
      acc[1][0] += a1 * b4.x; acc[1][1] += a1 * b4.y; acc[1][2] += a1 * b4.z; acc[1][3] += a1 * b4.w;
      acc[2][0] += a2 * b4.x; acc[2][1] += a2 * b4.y; acc[2][2] += a2 * b4.z; acc[2][3] += a2 * b4.w;
      acc[3][0] += a3 * b4.x; acc[3][1] += a3 * b4.y; acc[3][2] += a3 * b4.z; acc[3][3] += a3 * b4.w;
    }
    __syncthreads();  // everyone done reading src before overwrite of dst
#pragma unroll
    for (int r = 0; r < 4; ++r)
#pragma unroll
      for (int c = 0; c < 4; ++c) dst[iy4 + r][jx4 + c] = acc[r][c];
    __syncthreads();
  }

  // write P
  float* Pg = ws + OFF_P;
  for (int e = tid; e < 4096; e += 256) Pg[e] = M1[e >> 6][e & 63];

  // chains
  const int lane = tid & 63, wv = tid >> 6;
  float* W1g = ws + OFF_W1;
  float* Wg = ws + OFF_WOUT;
  float reg[64];
  if (wv == 0) {
    // vr[m] = A^m b, m = 0..63
#pragma unroll
    for (int j = 0; j < 64; ++j) reg[j] = Asv[lane][j];
    float cur = Bsh[lane];
    vrT[0][lane] = cur;
    W1g[lane * 128 + 127] = cur;
    for (int m = 1; m < 64; ++m) {
      float nv = 0.f;
#pragma unroll
      for (int j = 0; j < 64; ++j) nv += reg[j] * BC(cur, j);
      cur = nv;
      vrT[m][lane] = cur;
      W1g[lane * 128 + 127 - m] = cur;
    }
  } else if (wv == 1) {
    // vr[m], m = 64..127; start vr[64] = A^64 * b
#pragma unroll
    for (int j = 0; j < 64; ++j) reg[j] = Asv[lane][j];
    const float b0 = Bsh[lane];
    float cur = 0.f;
#pragma unroll
    for (int j = 0; j < 64; ++j) cur += M0[lane][j] * BC(b0, j);
    vrT[64][lane] = cur;
    W1g[lane * 128 + 63] = cur;
    for (int m = 65; m < 128; ++m) {
      float nv = 0.f;
#pragma unroll
      for (int j = 0; j < 64; ++j) nv += reg[j] * BC(cur, j);
      cur = nv;
      vrT[m][lane] = cur;
      W1g[lane * 128 + 127 - m] = cur;
    }
  } else if (wv == 2) {
    // cw[m] = c^T A^m, m = 1..64; Wout[.][m-1]
#pragma unroll
    for (int j = 0; j < 64; ++j) reg[j] = Asv[j][lane];  // A column lane
    float cur = Cs[lane];
    for (int m = 1; m <= 64; ++m) {
      float nv = 0.f;
#pragma unroll
      for (int j = 0; j < 64; ++j) nv += BC(cur, j) * reg[j];
      cur = nv;
      Wg[lane * 128 + m - 1] = cur;
    }
  } else {
    // cw[m], m = 65..128; start cw[64] = c^T A^64
#pragma unroll
    for (int j = 0; j < 64; ++j) reg[j] = Asv[j][lane];
    const float c0 = Cs[lane];
    float cur = 0.f;
#pragma unroll
    for (int j = 0; j < 64; ++j) cur += BC(c0, j) * M0[j][lane];
    for (int m = 65; m <= 128; ++m) {
      float nv = 0.f;
#pragma unroll
      for (int j = 0; j < 64; ++j) nv += BC(cur, j) * reg[j];
      cur = nv;
      Wg[lane * 128 + m - 1] = cur;
    }
  }
  __syncthreads();

  // Kloc: KlocZ[128+m] = sum_i C[i]*vr[m][i]; zeros in front as guard
  float* Kz = ws + OFF_KLOC;
  if (tid < 128) {
    float acc = 0.f;
#pragma unroll
    for (int i = 0; i < 64; ++i) acc += Cs[i] * vrT[tid][i];
    Kz[128 + tid] = acc;
  } else {
    Kz[tid - 128] = 0.f;
  }
}

// ===========================================================================
// k_scan: X_{c+1} = P X_c + sum_r (A^{127-r} b) u[c*128+r]; writes X_c
// (pre-chunk state) for every chunk. 1 sequence per wave, lane = state.
// W1 (128) and P (64) rows live in VGPRs; u broadcast via readlane (SGPR
// operand feeds v_fmac directly). No barriers; u prefetched a chunk ahead.
// ===========================================================================
__global__ __launch_bounds__(256, 2) void k_scan(
    const float* __restrict__ u, const float* __restrict__ wsr,
    float* __restrict__ xs) {
  const int lane = threadIdx.x & 63, wv = threadIdx.x >> 6;
  const int s = blockIdx.x * 4 + wv;
  const int bi = s >> 9, d = s & 511;

  float p[64], w1[128];
  {
    const float* pr = wsr + OFF_P + lane * 64;
#pragma unroll
    for (int j = 0; j < 64; j += 4) {
      const float4 v = *(const float4*)(pr + j);
      p[j] = v.x; p[j + 1] = v.y; p[j + 2] = v.z; p[j + 3] = v.w;
    }
    const float* wr = wsr + OFF_W1 + lane * 128;
#pragma unroll
    for (int j = 0; j < 128; j += 4) {
      const float4 v = *(const float4*)(wr + j);
      w1[j] = v.x; w1[j + 1] = v.y; w1[j + 2] = v.z; w1[j + 3] = v.w;
    }
  }

  const float* ub = u + (size_t)bi * L_SEQ * D_MODEL + d;
  float x = 0.f;
  float u0 = ub[(size_t)lane * D_MODEL];
  float u1 = ub[(size_t)(64 + lane) * D_MODEL];

  for (int c = 0; c < NC; ++c) {
    float u0n = 0.f, u1n = 0.f;
    if (c + 1 < NC) {
      u0n = ub[(size_t)((c + 1) * CH + lane) * D_MODEL];
      u1n = ub[(size_t)((c + 1) * CH + 64 + lane) * D_MODEL];
    }
    xs[(size_t)(c * 64 + lane) * NSEQ + s] = x;  // pre-chunk state X_c
    float xn = 0.f;
#pragma unroll
    for (int r = 0; r < 64; ++r) xn += w1[r] * BC(u0, r);
#pragma unroll
    for (int r = 0; r < 64; ++r) xn += w1[64 + r] * BC(u1, r);
#pragma unroll
    for (int j = 0; j < 64; ++j) xn += p[j] * BC(x, j);
    x = xn;
    u0 = u0n;
    u1 = u1n;
  }
}

// ===========================================================================
// k_localout: y[c*128+r][s] = sum_{r'<=r} Kloc[r-r'] u[c*128+r'][s]
//                           + sum_i Wout[i][r] * X_c[i][s]
// 64 rows x 128 seqs per block; K = 64*(par+1) Toeplitz + 64 dense.
// fp32 LDS-GEMM, 4x8 register micro-tiles (R1-proven ~70% VALU pattern).
// ===========================================================================
__global__ __launch_bounds__(256) void k_localout(
    const float* __restrict__ u, const float* __restrict__ wsr,
    float* __restrict__ out) {
  __shared__ float As[64][68];    // As[k][row]
  __shared__ float Bs[64][132];   // Bs[k][s]

  const int sg = blockIdx.x;      // 0..15 (128 seqs each)
  const int tr = blockIdx.y;      // 0..63 (64 rows each)
  const int c = tr >> 1, par = tr & 1;
  const int r0 = par * 64;
  const int sgl = sg * 128;
  const int bi = sgl >> 9, d0 = sgl & 511;

  const float* KlocZ = wsr + OFF_KLOC;
  const float* WoutG = wsr + OFF_WOUT;
  const float* xs = wsr + OFF_XS;
  const float* ub = u + ((size_t)bi * L_SEQ + c * CH) * D_MODEL + d0;

  const int tid = threadIdx.x;
  const int ty4 = (tid >> 4) * 4;
  const int tx8 = (tid & 15) * 8;

  float acc[4][8];
#pragma unroll
  for (int r = 0; r < 4; ++r)
#pragma unroll
    for (int cc = 0; cc < 8; ++cc) acc[r][cc] = 0.f;

  // phase A: within-chunk Toeplitz part
  for (int kt = 0; kt <= par; ++kt) {
    const int k0 = kt * 64;
#pragma unroll
    for (int e8 = 0; e8 < 8; ++e8) {
      const int e = tid + 256 * e8;          // 2048 float4 chunks
      const int kk = e >> 5, s4 = (e & 31) * 4;
      *(float4*)&Bs[kk][s4] = *(const float4*)(ub + (size_t)(k0 + kk) * D_MODEL + s4);
    }
    const int base = 128 + r0 - k0;
#pragma unroll
    for (int e4 = 0; e4 < 16; ++e4) {
      const int e = tid + 256 * e4;
      const int kk = e >> 6, i = e & 63;
      As[kk][i] = KlocZ[base + i - kk];      // zero-guarded Toeplitz
    }
    __syncthreads();
#pragma unroll 4
    for (int kk = 0; kk < 64; ++kk) {
      const float4 a = *(const float4*)&As[kk][ty4];
      const float4 b0 = *(const float4*)&Bs[kk][tx8];
      const float4 b1 = *(const float4*)&Bs[kk][tx8 + 4];
      acc[0][0] += a.x * b0.x; acc[0][1] += a.x * b0.y; acc[0][2] += a.x * b0.z; acc[0][3] += a.x * b0.w;
      acc[0][4] += a.x * b1.x; acc[0][5] += a.x * b1.y; acc[0][6] += a.x * b1.z; acc[0][7] += a.x * b1.w;
      acc[1][0] += a.y * b0.x; acc[1][1] += a.y * b0.y; acc[1][2] += a.y * b0.z; acc[1][3] += a.y * b0.w;
      acc[1][4] += a.y * b1.x; acc[1][5] += a.y * b1.y; acc[1][6] += a.y * b1.z; acc[1][7] += a.y * b1.w;
      acc[2][0] += a.z * b0.x; acc[2][1] += a.z * b0.y; acc[2][2] += a.z * b0.z; acc[2][3] += a.z * b0.w;
      acc[2][4] += a.z * b1.x; acc[2][5] += a.z * b1.y; acc[2][6] += a.z * b1.z; acc[2][7] += a.z * b1.w;
      acc[3][0] += a.w * b0.x; acc[3][1] += a.w * b0.y; acc[3][2] += a.w * b0.z; acc[3][3] += a.w * b0.w;
      acc[3][4] += a.w * b1.x; acc[3][5] += a.w * b1.y; acc[3][6] += a.w * b1.z; acc[3][7] += a.w * b1.w;
    }
    __syncthreads();
  }

  // phase B: Wout * X_c
  {
    const float* xc = xs + (size_t)c * 64 * NSEQ + sgl;
#pragma unroll
    for (int e8 = 0; e8 < 8; ++e8) {
      const int e = tid + 256 * e8;
      const int i_ = e >> 5, s4 = (e & 31) * 4;
      *(float4*)&Bs[i_][s4] = *(const float4*)(xc + (size_t)i_ * NSEQ + s4);
    }
#pragma unroll
    for (int e4 = 0; e4 < 16; ++e4) {
      const int e = tid + 256 * e4;
      const int i_ = e >> 6, r = e & 63;
      As[i_][r] = WoutG[i_ * 128 + r0 + r];
    }
    __syncthreads();
#pragma unroll 4
    for (int kk = 0; kk < 64; ++kk) {
      const float4 a = *(const float4*)&As[kk][ty4];
      const float4 b0 = *(const float4*)&Bs[kk][tx8];
      const float4 b1 = *(const float4*)&Bs[kk][tx8 + 4];
      acc[0][0] += a.x * b0.x; acc[0][1] += a.x * b0.y; acc[0][2] += a.x * b0.z; acc[0][3] += a.x * b0.w;
      acc[0][4] += a.x * b1.x; acc[0][5] += a.x * b1.y; acc[0][6] += a.x * b1.z; acc[0][7] += a.x * b1.w;
      acc[1][0] += a.y * b0.x; acc[1][1] += a.y * b0.y; acc[1][2] += a.y * b0.z; acc[1][3] += a.y * b0.w;
      acc[1][4] += a.y * b1.x; acc[1][5] += a.y * b1.y; acc[1][6] += a.y * b1.z; acc[1][7] += a.y * b1.w;
      acc[2][0] += a.z * b0.x; acc[2][1] += a.z * b0.y; acc[2][2] += a.z * b0.z; acc[2][3] += a.z * b0.w;
      acc[2][4] += a.z * b1.x; acc[2][5] += a.z * b1.y; acc[2][6] += a.z * b1.z; acc[2][7] += a.z * b1.w;
      acc[3][0] += a.w * b0.x; acc[3][1] += a.w * b0.y; acc[3][2] += a.w * b0.z; acc[3][3] += a.w * b0.w;
      acc[3][4] += a.w * b1.x; acc[3][5] += a.w * b1.y; acc[3][6] += a.w * b1.z; acc[3][7] += a.w * b1.w;
    }
  }

  // epilogue
  float* ob = out + ((size_t)bi * L_SEQ + c * CH + r0) * D_MODEL + d0;
#pragma unroll
  for (int r = 0; r < 4; ++r) {
    float4 v0, v1;
    v0.x = acc[r][0]; v0.y = acc[r][1]; v0.z = acc[r][2]; v0.w = acc[r][3];
    v1.x = acc[r][4]; v1.y = acc[r][5]; v1.z = acc[r][6]; v1.w = acc[r][7];
    float* row = ob + (size_t)(ty4 + r) * D_MODEL + tx8;
    *(float4*)row = v0;
    *(float4*)(row + 4) = v1;
  }
}

extern "C" void kernel_launch(void* const* d_in, const int* in_sizes, int n_in,
                              void* d_out, int out_size, void* d_ws,
                              size_t ws_size, hipStream_t stream) {
  const float* u = (const float*)d_in[0];   // (4, 4096, 512)
  const float* A = (const float*)d_in[1];   // (64, 64)
  const float* B = (const float*)d_in[2];   // (64, 1)
  const float* C = (const float*)d_in[3];   // (1, 64)
  float* out = (float*)d_out;
  float* ws = (float*)d_ws;                 // needs ~16.9 MB (have >=33.6 MB)

  k_prep<<<1, 256, 0, stream>>>(A, B, C, ws);
  k_scan<<<512, 256, 0, stream>>>(u, ws, ws + OFF_XS);
  k_localout<<<dim3(16, 64), 256, 0, stream>>>(u, ws, out);
}

// Round 5
// 209.281 us; speedup vs baseline: 1.5076x; 1.1785x over previous
//
#include <hip/hip_runtime.h>

#define L_SEQ   4096
#define D_MODEL 512
#define NSEQ    2048   // BATCH * D_MODEL
#define CH      128    // chunk length
#define NC      32     // chunks

// workspace float offsets
#define OFF_P    0        // P = A^128, [i][j] row-major, 4096
#define OFF_W1T  4096     // W1T[r][i] = (A^{127-r} b)[i], 128x64
#define OFF_WOUT 12288    // Wout[i][r] = (c^T A^{r+1})[i], 64x128
#define OFF_KLOC 20480    // KlocZ[0..127]=0, KlocZ[128+m]=c^T A^m b, 256
#define OFF_GX   20736    // gx[c][s][i]: proj writes G, scan overwrites X_c

#define BC(v, j) __int_as_float(__builtin_amdgcn_readlane(__float_as_int(v), (j)))

// ===========================================================================
// k_prep (1 block): P=A^128 via 7 LDS squarings; four 64-step chains in 4
// parallel waves (halves split via A^64): W1T, Wout, Kloc tables.
// ===========================================================================
__global__ __launch_bounds__(256) void k_prep(
    const float* __restrict__ A, const float* __restrict__ B,
    const float* __restrict__ C, float* __restrict__ ws) {
  __shared__ float M0[64][68];
  __shared__ float M1[64][68];
  __shared__ float Asv[64][68];
  __shared__ float vrT[128][65];  // vrT[m][i] = (A^m b)[i]
  __shared__ float Cs[64], Bsh[64];

  const int tid = threadIdx.x;
  if (tid < 64) { Cs[tid] = C[tid]; Bsh[tid] = B[tid]; }
  for (int e = tid; e < 4096; e += 256) {
    const float a = A[e];
    M0[e >> 6][e & 63] = a;
    Asv[e >> 6][e & 63] = a;
  }
  __syncthreads();

  // 7 squarings: after it=5 M0=A^64, after it=6 M1=A^128
  const int iy4 = (tid >> 4) * 4, jx4 = (tid & 15) * 4;
  for (int it = 0; it < 7; ++it) {
    float (*src)[68] = (it & 1) ? M1 : M0;
    float (*dst)[68] = (it & 1) ? M0 : M1;
    float acc[4][4] = {{0.f}};
#pragma unroll 8
    for (int k = 0; k < 64; ++k) {
      const float a0 = src[iy4 + 0][k];
      const float a1 = src[iy4 + 1][k];
      const float a2 = src[iy4 + 2][k];
      const float a3 = src[iy4 + 3][k];
      const float4 b4 = *(const float4*)&src[k][jx4];
      acc[0][0] += a0 * b4.x; acc[0][1] += a0 * b4.y; acc[0][2] += a0 * b4.z; acc[0][3] += a0 * b4.w;
      acc[1][0] += a1 * b4.x; acc[1][1] += a1 * b4.y; acc[1][2] += a1 * b4.z; acc[1][3] += a1 * b4.w;
      acc[2][0] += a2 * b4.x; acc[2][1] += a2 * b4.y; acc[2][2] += a2 * b4.z; acc[2][3] += a2 * b4.w;
      acc[3][0] += a3 * b4.x; acc[3][1] += a3 * b4.y; acc[3][2] += a3 * b4.z; acc[3][3] += a3 * b4.w;
    }
    __syncthreads();
#pragma unroll
    for (int r = 0; r < 4; ++r)
#pragma unroll
      for (int c = 0; c < 4; ++c) dst[iy4 + r][jx4 + c] = acc[r][c];
    __syncthreads();
  }

  // write P
  float* Pg = ws + OFF_P;
  for (int e = tid; e < 4096; e += 256) Pg[e] = M1[e >> 6][e & 63];

  // chains
  const int lane = tid & 63, wv = tid >> 6;
  float* Wg = ws + OFF_WOUT;
  float reg[64];
  if (wv == 0) {
    // vr[m] = A^m b, m = 0..63
#pragma unroll
    for (int j = 0; j < 64; ++j) reg[j] = Asv[lane][j];
    float cur = Bsh[lane];
    vrT[0][lane] = cur;
    for (int m = 1; m < 64; ++m) {
      float nv = 0.f;
#pragma unroll
      for (int j = 0; j < 64; ++j) nv += reg[j] * BC(cur, j);
      cur = nv;
      vrT[m][lane] = cur;
    }
  } else if (wv == 1) {
    // vr[m], m = 64..127; start vr[64] = A^64 * b
#pragma unroll
    for (int j = 0; j < 64; ++j) reg[j] = Asv[lane][j];
    const float b0 = Bsh[lane];
    float cur = 0.f;
#pragma unroll
    for (int j = 0; j < 64; ++j) cur += M0[lane][j] * BC(b0, j);
    vrT[64][lane] = cur;
    for (int m = 65; m < 128; ++m) {
      float nv = 0.f;
#pragma unroll
      for (int j = 0; j < 64; ++j) nv += reg[j] * BC(cur, j);
      cur = nv;
      vrT[m][lane] = cur;
    }
  } else if (wv == 2) {
    // cw[m] = c^T A^m, m = 1..64; Wout[.][m-1]
#pragma unroll
    for (int j = 0; j < 64; ++j) reg[j] = Asv[j][lane];  // A column lane
    float cur = Cs[lane];
    for (int m = 1; m <= 64; ++m) {
      float nv = 0.f;
#pragma unroll
      for (int j = 0; j < 64; ++j) nv += BC(cur, j) * reg[j];
      cur = nv;
      Wg[lane * 128 + m - 1] = cur;
    }
  } else {
    // cw[m], m = 65..128; start cw[64] = c^T A^64
#pragma unroll
    for (int j = 0; j < 64; ++j) reg[j] = Asv[j][lane];
    const float c0 = Cs[lane];
    float cur = 0.f;
#pragma unroll
    for (int j = 0; j < 64; ++j) cur += BC(c0, j) * M0[j][lane];
    for (int m = 65; m <= 128; ++m) {
      float nv = 0.f;
#pragma unroll
      for (int j = 0; j < 64; ++j) nv += BC(cur, j) * reg[j];
      cur = nv;
      Wg[lane * 128 + m - 1] = cur;
    }
  }
  __syncthreads();

  // W1T[r][i] = vr[127-r][i]  (coalesced)
  float* W1Tg = ws + OFF_W1T;
  for (int e = tid; e < 8192; e += 256) {
    const int r = e >> 6, i = e & 63;
    W1Tg[e] = vrT[127 - r][i];
  }

  // Kloc: KlocZ[128+m] = sum_i C[i]*vr[m][i]; zeros in front as guard
  float* Kz = ws + OFF_KLOC;
  if (tid < 128) {
    float acc = 0.f;
#pragma unroll
    for (int i = 0; i < 64; ++i) acc += Cs[i] * vrT[tid][i];
    Kz[128 + tid] = acc;
  } else {
    Kz[tid - 128] = 0.f;
  }
}

// ===========================================================================
// k_proj: G[c][s][i] = sum_r W1T[r][i] * u[c*128+r][s]
// Per block: one (chunk, 128-seq tile) -> 128x64 output, K=128 (two 64-r
// halves through LDS). fp32 LDS-GEMM, 4x8 micro-tiles.
// ===========================================================================
__global__ __launch_bounds__(256) void k_proj(
    const float* __restrict__ u, const float* __restrict__ wsr,
    float* __restrict__ gx) {
  __shared__ float W1s[128][66];
  __shared__ float Us[64][132];

  const int st = blockIdx.x;   // 0..15
  const int c = blockIdx.y;    // 0..31
  const int tid = threadIdx.x;
  const int sgl = st * 128;
  const int bi = sgl >> 9, d0 = sgl & 511;

  const float* W1Tg = wsr + OFF_W1T;
#pragma unroll
  for (int k = 0; k < 32; ++k) {
    const int e = tid + 256 * k;
    W1s[e >> 6][e & 63] = W1Tg[e];
  }

  const float* ub = u + ((size_t)bi * L_SEQ + c * CH) * D_MODEL + d0;
  const int sy4 = (tid >> 3) * 4;   // s-row group (0..31)*4
  const int ix8 = (tid & 7) * 8;    // i-col group (0..7)*8

  float acc[4][8];
#pragma unroll
  for (int r = 0; r < 4; ++r)
#pragma unroll
    for (int cc = 0; cc < 8; ++cc) acc[r][cc] = 0.f;

  for (int h = 0; h < 2; ++h) {
    __syncthreads();
#pragma unroll
    for (int e8 = 0; e8 < 8; ++e8) {
      const int e = tid + 256 * e8;
      const int rr = e >> 5, s4 = (e & 31) * 4;
      *(float4*)&Us[rr][s4] =
          *(const float4*)(ub + (size_t)(h * 64 + rr) * D_MODEL + s4);
    }
    __syncthreads();
#pragma unroll 4
    for (int rr = 0; rr < 64; ++rr) {
      const int r = h * 64 + rr;
      const float4 a = *(const float4*)&Us[rr][sy4];
      const float4 b0 = *(const float4*)&W1s[r][ix8];
      const float4 b1 = *(const float4*)&W1s[r][ix8 + 4];
      acc[0][0] += a.x * b0.x; acc[0][1] += a.x * b0.y; acc[0][2] += a.x * b0.z; acc[0][3] += a.x * b0.w;
      acc[0][4] += a.x * b1.x; acc[0][5] += a.x * b1.y; acc[0][6] += a.x * b1.z; acc[0][7] += a.x * b1.w;
      acc[1][0] += a.y * b0.x; acc[1][1] += a.y * b0.y; acc[1][2] += a.y * b0.z; acc[1][3] += a.y * b0.w;
      acc[1][4] += a.y * b1.x; acc[1][5] += a.y * b1.y; acc[1][6] += a.y * b1.z; acc[1][7] += a.y * b1.w;
      acc[2][0] += a.z * b0.x; acc[2][1] += a.z * b0.y; acc[2][2] += a.z * b0.z; acc[2][3] += a.z * b0.w;
      acc[2][4] += a.z * b1.x; acc[2][5] += a.z * b1.y; acc[2][6] += a.z * b1.z; acc[2][7] += a.z * b1.w;
      acc[3][0] += a.w * b0.x; acc[3][1] += a.w * b0.y; acc[3][2] += a.w * b0.z; acc[3][3] += a.w * b0.w;
      acc[3][4] += a.w * b1.x; acc[3][5] += a.w * b1.y; acc[3][6] += a.w * b1.z; acc[3][7] += a.w * b1.w;
    }
  }

  float* gb = gx + ((size_t)c * NSEQ + sgl) * 64;
#pragma unroll
  for (int as = 0; as < 4; ++as) {
    float4 v0, v1;
    v0.x = acc[as][0]; v0.y = acc[as][1]; v0.z = acc[as][2]; v0.w = acc[as][3];
    v1.x = acc[as][4]; v1.y = acc[as][5]; v1.z = acc[as][6]; v1.w = acc[as][7];
    float* row = gb + (size_t)(sy4 + as) * 64 + ix8;
    *(float4*)row = v0;
    *(float4*)(row + 4) = v1;
  }
}

// ===========================================================================
// k_scan: x_{c+1} = P x_c + g_c. One seq per wave, lane = state.
// Only P row (64 floats) lives in VGPRs (promotable). g read and X_c write
// are fully coalesced (256 B/wave, [c][s][i] layout); g[c] is overwritten
// in place by X_c after its final read.
// ===========================================================================
__global__ __launch_bounds__(256) void k_scan(
    const float* __restrict__ wsr, float* __restrict__ gx) {
  const int lane = threadIdx.x & 63, wv = threadIdx.x >> 6;
  const int s = blockIdx.x * 4 + wv;

  float p[64];
  {
    const float* pr = wsr + OFF_P + lane * 64;
#pragma unroll
    for (int j = 0; j < 64; j += 4) {
      const float4 v = *(const float4*)(pr + j);
      p[j] = v.x; p[j + 1] = v.y; p[j + 2] = v.z; p[j + 3] = v.w;
    }
  }

  float* gs = gx + (size_t)s * 64 + lane;
  float x = 0.f;
  float g = gs[0];
  for (int c = 0; c < NC; ++c) {
    const float gn = (c + 1 < NC) ? gs[(size_t)(c + 1) * NSEQ * 64] : 0.f;
    gs[(size_t)c * NSEQ * 64] = x;  // overwrite g[c] with pre-chunk state X_c
    float x0 = g, x1 = 0.f;
#pragma unroll
    for (int j = 0; j < 64; j += 2) {
      x0 += p[j] * BC(x, j);
      x1 += p[j + 1] * BC(x, j + 1);
    }
    x = x0 + x1;
    g = gn;
  }
}

// ===========================================================================
// k_localout: y[c*128+r][s] = sum_{r'<=r} Kloc[r-r'] u[c*128+r'][s]
//                           + sum_i Wout[i][r] * X_c[i][s]
// 64 rows x 128 seqs per block. fp32 LDS-GEMM, 4x8 micro-tiles.
// Phase B stages X_c from the [c][s][i] layout via float4 + LDS transpose.
// ===========================================================================
__global__ __launch_bounds__(256) void k_localout(
    const float* __restrict__ u, const float* __restrict__ wsr,
    const float* __restrict__ gx, float* __restrict__ out) {
  __shared__ float As[64][68];    // As[k][row]
  __shared__ float Bs[64][132];   // Bs[k][s]

  const int sg = blockIdx.x;      // 0..15 (128 seqs each)
  const int tr = blockIdx.y;      // 0..63 (64 rows each)
  const int c = tr >> 1, par = tr & 1;
  const int r0 = par * 64;
  const int sgl = sg * 128;
  const int bi = sgl >> 9, d0 = sgl & 511;

  const float* KlocZ = wsr + OFF_KLOC;
  const float* WoutG = wsr + OFF_WOUT;
  const float* ub = u + ((size_t)bi * L_SEQ + c * CH) * D_MODEL + d0;

  const int tid = threadIdx.x;
  const int ty4 = (tid >> 4) * 4;
  const int tx8 = (tid & 15) * 8;

  float acc[4][8];
#pragma unroll
  for (int r = 0; r < 4; ++r)
#pragma unroll
    for (int cc = 0; cc < 8; ++cc) acc[r][cc] = 0.f;

  // phase A: within-chunk Toeplitz part
  for (int kt = 0; kt <= par; ++kt) {
    const int k0 = kt * 64;
#pragma unroll
    for (int e8 = 0; e8 < 8; ++e8) {
      const int e = tid + 256 * e8;          // 2048 float4 chunks
      const int kk = e >> 5, s4 = (e & 31) * 4;
      *(float4*)&Bs[kk][s4] = *(const float4*)(ub + (size_t)(k0 + kk) * D_MODEL + s4);
    }
    const int base = 128 + r0 - k0;
#pragma unroll
    for (int e4 = 0; e4 < 16; ++e4) {
      const int e = tid + 256 * e4;
      const int kk = e >> 6, i = e & 63;
      As[kk][i] = KlocZ[base + i - kk];      // zero-guarded Toeplitz
    }
    __syncthreads();
#pragma unroll 4
    for (int kk = 0; kk < 64; ++kk) {
      const float4 a = *(const float4*)&As[kk][ty4];
      const float4 b0 = *(const float4*)&Bs[kk][tx8];
      const float4 b1 = *(const float4*)&Bs[kk][tx8 + 4];
      acc[0][0] += a.x * b0.x; acc[0][1] += a.x * b0.y; acc[0][2] += a.x * b0.z; acc[0][3] += a.x * b0.w;
      acc[0][4] += a.x * b1.x; acc[0][5] += a.x * b1.y; acc[0][6] += a.x * b1.z; acc[0][7] += a.x * b1.w;
      acc[1][0] += a.y * b0.x; acc[1][1] += a.y * b0.y; acc[1][2] += a.y * b0.z; acc[1][3] += a.y * b0.w;
      acc[1][4] += a.y * b1.x; acc[1][5] += a.y * b1.y; acc[1][6] += a.y * b1.z; acc[1][7] += a.y * b1.w;
      acc[2][0] += a.z * b0.x; acc[2][1] += a.z * b0.y; acc[2][2] += a.z * b0.z; acc[2][3] += a.z * b0.w;
      acc[2][4] += a.z * b1.x; acc[2][5] += a.z * b1.y; acc[2][6] += a.z * b1.z; acc[2][7] += a.z * b1.w;
      acc[3][0] += a.w * b0.x; acc[3][1] += a.w * b0.y; acc[3][2] += a.w * b0.z; acc[3][3] += a.w * b0.w;
      acc[3][4] += a.w * b1.x; acc[3][5] += a.w * b1.y; acc[3][6] += a.w * b1.z; acc[3][7] += a.w * b1.w;
    }
    __syncthreads();
  }

  // phase B: Wout * X_c  (X from gx[c][s][i] via float4 + LDS transpose)
  {
    const float* xc = gx + ((size_t)c * NSEQ + sgl) * 64;
#pragma unroll
    for (int e8 = 0; e8 < 8; ++e8) {
      const int e = tid + 256 * e8;          // 2048 float4 = 8192 elems
      const int sl = e >> 4, i4 = (e & 15) * 4;
      const float4 v = *(const float4*)(xc + (size_t)sl * 64 + i4);
      Bs[i4 + 0][sl] = v.x;
      Bs[i4 + 1][sl] = v.y;
      Bs[i4 + 2][sl] = v.z;
      Bs[i4 + 3][sl] = v.w;
    }
#pragma unroll
    for (int e4 = 0; e4 < 16; ++e4) {
      const int e = tid + 256 * e4;
      const int i_ = e >> 6, r = e & 63;
      As[i_][r] = WoutG[i_ * 128 + r0 + r];
    }
    __syncthreads();
#pragma unroll 4
    for (int kk = 0; kk < 64; ++kk) {
      const float4 a = *(const float4*)&As[kk][ty4];
      const float4 b0 = *(const float4*)&Bs[kk][tx8];
      const float4 b1 = *(const float4*)&Bs[kk][tx8 + 4];
      acc[0][0] += a.x * b0.x; acc[0][1] += a.x * b0.y; acc[0][2] += a.x * b0.z; acc[0][3] += a.x * b0.w;
      acc[0][4] += a.x * b1.x; acc[0][5] += a.x * b1.y; acc[0][6] += a.x * b1.z; acc[0][7] += a.x * b1.w;
      acc[1][0] += a.y * b0.x; acc[1][1] += a.y * b0.y; acc[1][2] += a.y * b0.z; acc[1][3] += a.y * b0.w;
      acc[1][4] += a.y * b1.x; acc[1][5] += a.y * b1.y; acc[1][6] += a.y * b1.z; acc[1][7] += a.y * b1.w;
      acc[2][0] += a.z * b0.x; acc[2][1] += a.z * b0.y; acc[2][2] += a.z * b0.z; acc[2][3] += a.z * b0.w;
      acc[2][4] += a.z * b1.x; acc[2][5] += a.z * b1.y; acc[2][6] += a.z * b1.z; acc[2][7] += a.z * b1.w;
      acc[3][0] += a.w * b0.x; acc[3][1] += a.w * b0.y; acc[3][2] += a.w * b0.z; acc[3][3] += a.w * b0.w;
      acc[3][4] += a.w * b1.x; acc[3][5] += a.w * b1.y; acc[3][6] += a.w * b1.z; acc[3][7] += a.w * b1.w;
    }
  }

  // epilogue
  float* ob = out + ((size_t)bi * L_SEQ + c * CH + r0) * D_MODEL + d0;
#pragma unroll
  for (int r = 0; r < 4; ++r) {
    float4 v0, v1;
    v0.x = acc[r][0]; v0.y = acc[r][1]; v0.z = acc[r][2]; v0.w = acc[r][3];
    v1.x = acc[r][4]; v1.y = acc[r][5]; v1.z = acc[r][6]; v1.w = acc[r][7];
    float* row = ob + (size_t)(ty4 + r) * D_MODEL + tx8;
    *(float4*)row = v0;
    *(float4*)(row + 4) = v1;
  }
}

extern "C" void kernel_launch(void* const* d_in, const int* in_sizes, int n_in,
                              void* d_out, int out_size, void* d_ws,
                              size_t ws_size, hipStream_t stream) {
  const float* u = (const float*)d_in[0];   // (4, 4096, 512)
  const float* A = (const float*)d_in[1];   // (64, 64)
  const float* B = (const float*)d_in[2];   // (64, 1)
  const float* C = (const float*)d_in[3];   // (1, 64)
  float* out = (float*)d_out;
  float* ws = (float*)d_ws;                 // needs ~16.9 MB
  float* gx = ws + OFF_GX;

  k_prep<<<1, 256, 0, stream>>>(A, B, C, ws);
  k_proj<<<dim3(16, 32), 256, 0, stream>>>(u, ws, gx);
  k_scan<<<512, 256, 0, stream>>>(ws, gx);
  k_localout<<<dim3(16, 64), 256, 0, stream>>>(u, ws, gx, out);
}